// Round 12
// baseline (180.130 us; speedup 1.0000x reference)
//
#include <hip/hip_runtime.h>

#define EPSV 1e-5f

typedef __bf16 bf16_t;
typedef __bf16 bf16x8 __attribute__((ext_vector_type(8)));
typedef float f32x4 __attribute__((ext_vector_type(4)));

__device__ inline bf16x8 bzero8() {
  bf16x8 z;
#pragma unroll
  for (int i = 0; i < 8; i++) z[i] = (bf16_t)0.f;
  return z;
}

__device__ inline f32x4 mfma16(bf16x8 a, bf16x8 b, f32x4 c) {
  return __builtin_amdgcn_mfma_f32_16x16x32_bf16(a, b, c, 0, 0, 0);
}

// ---------------- weight prep: fp32 -> bf16, padded + reordered ----------------
// w1b [160][608]        (row=oc, k=ic)               oc>=152 zero
// w2b [384][1376]       (row=oc, k=tap*152+ic)       pads zero
// wdb [192][1440]       (row=o,  k=tap*160+ic)       pads zero (per-tap slice padded to 160)
// w3b [640][160]        (row=oc, k=ic)               k>=152 / oc>=608 zero
#define W1E (160 * 608)
#define W2E (384 * 1376)
#define WDE (192 * 1440)
#define W3E (640 * 160)

__global__ __launch_bounds__(256) void prep_weights(
    const float* __restrict__ w1, const float* __restrict__ w2,
    const float* __restrict__ wd, const float* __restrict__ w3,
    bf16_t* __restrict__ w1b, bf16_t* __restrict__ w2b,
    bf16_t* __restrict__ wdb, bf16_t* __restrict__ w3b) {
  int i = blockIdx.x * 256 + threadIdx.x;
  float v = 0.f;
  if (i < W1E) {
    int oc = i / 608, ic = i % 608;
    if (oc < 152) v = w1[oc * 608 + ic];
    w1b[i] = (bf16_t)v;
  } else if (i < W1E + W2E) {
    int j = i - W1E;
    int oc = j / 1376, k = j % 1376;
    if (oc < 342 && k < 1368) {
      int t = k / 152, ic = k % 152;
      v = w2[(oc * 152 + ic) * 9 + t];
    }
    w2b[j] = (bf16_t)v;
  } else if (i < W1E + W2E + WDE) {
    int j = i - W1E - W2E;
    int o = j / 1440, k = j % 1440;
    int t = k / 160, ic = k % 160;
    if (o < 152 && ic < 152) v = wd[(o * 152 + ic) * 9 + t];
    wdb[j] = (bf16_t)v;
  } else if (i < W1E + W2E + WDE + W3E) {
    int j = i - W1E - W2E - WDE;
    int oc = j / 160, ic = j % 160;
    if (oc < 608 && ic < 152) v = w3[oc * 152 + ic];
    w3b[j] = (bf16_t)v;
  }
}

// bnc layout: [0,152) inv1, [152,304) beta1, [304,456) inv2, [456,608) beta2,
//             [608,1216) inv3, [1216,1824) beta3
__global__ void prep_bn(const float* g1, const float* b1, const float* m1, const float* v1,
                        const float* g2, const float* b2, const float* m2, const float* v2,
                        const float* g3, const float* b3, const float* m3, const float* v3,
                        float* __restrict__ bnc) {
  int i = threadIdx.x;
  if (i < 152) {
    float inv = g1[i] / sqrtf(v1[i] + EPSV);
    bnc[i] = inv;
    bnc[152 + i] = b1[i] - m1[i] * inv;
    float inv2 = g2[i] / sqrtf(v2[i] + EPSV);
    bnc[304 + i] = inv2;
    bnc[456 + i] = b2[i] - m2[i] * inv2;
  }
  if (i < 608) {
    float inv3 = g3[i] / sqrtf(v3[i] + EPSV);
    bnc[608 + i] = inv3;
    bnc[1216 + i] = b3[i] - m3[i] * inv3;
  }
}

// ---------------- S1: conv1 1x1 (K=608,N=152) + relu + bn1 -> out1 NHWC bf16 ----------------
__global__ __launch_bounds__(256) void s1_conv1(const float* __restrict__ x,
                                                const bf16_t* __restrict__ w1b,
                                                const float* __restrict__ bnc,
                                                bf16_t* __restrict__ out1) {
  __shared__ bf16_t t1[32 * 616];  // 38.5 KB
  int tid = threadIdx.x;
  int px0 = blockIdx.x * 32;
  int b = px0 >> 12, sp0 = px0 & 4095;
  for (int task = tid; task < 608 * 8; task += 256) {
    int c = task >> 3, i4 = task & 7;
    f32x4 v = *(const f32x4*)(x + (((size_t)(b * 608 + c)) << 12) + sp0 + i4 * 4);
#pragma unroll
    for (int i = 0; i < 4; i++) t1[(i4 * 4 + i) * 616 + c] = (bf16_t)v[i];
  }
  __syncthreads();
  int wid = tid >> 6, lane = tid & 63, q = lane >> 4, lr = lane & 15;
  int mw = wid & 1, nw = wid >> 1;  // 2M x 2N
  f32x4 acc[5];
#pragma unroll
  for (int n = 0; n < 5; n++) acc[n] = (f32x4){0.f, 0.f, 0.f, 0.f};
  for (int kk = 0; kk < 19; kk++) {
    int k0 = kk * 32 + q * 8;
    bf16x8 a = *(const bf16x8*)(t1 + (mw * 16 + lr) * 616 + k0);
#pragma unroll
    for (int n = 0; n < 5; n++) {
      bf16x8 bf = *(const bf16x8*)(w1b + (nw * 80 + n * 16 + lr) * 608 + k0);
      acc[n] = mfma16(a, bf, acc[n]);
    }
  }
#pragma unroll
  for (int n = 0; n < 5; n++) {
    int oc = nw * 80 + n * 16 + lr;
    if (oc < 152) {
      float inv = bnc[oc], beta = bnc[152 + oc];
#pragma unroll
      for (int i = 0; i < 4; i++) {
        int p = px0 + mw * 16 + q * 4 + i;
        float v = fmaxf(acc[n][i], 0.f) * inv + beta;
        out1[(size_t)p * 152 + oc] = (bf16_t)v;
      }
    }
  }
}

// ---------------- S2: offset conv 3x3 (K=1368->1376, N=342->384) -> offs fp32 [pix][col] ----------------
__global__ __launch_bounds__(256, 4) void s2_offs(const bf16_t* __restrict__ out1,
                                                  const bf16_t* __restrict__ w2b,
                                                  float* __restrict__ offs) {
  __shared__ bf16_t t2[3 * 34 * 156];  // 31.8 KB
  int tid = threadIdx.x;
  int nh = blockIdx.x & 1;
  int rest = blockIdx.x >> 1;
  int xh = rest & 1, y = (rest >> 1) & 63, b = rest >> 7;
  const bf16_t* ob = out1 + (((size_t)b) << 12) * 152;
  int x0 = xh * 32 - 1;
  for (int task = tid; task < 3 * 34 * 19; task += 256) {
    int j = task / 646, r = task % 646;
    int xi = r / 19, cb = r % 19;
    int yy = y + j - 1, xx = x0 + xi;
    bf16x8 v = bzero8();
    if (yy >= 0 && yy < 64 && xx >= 0 && xx < 64)
      v = *(const bf16x8*)(ob + (size_t)(yy * 64 + xx) * 152 + cb * 8);
    *(bf16x8*)(t2 + (j * 34 + xi) * 156 + cb * 8) = v;
  }
  __syncthreads();
  int wid = tid >> 6, lane = tid & 63, q = lane >> 4, lr = lane & 15;
  int ncol0 = nh * 192 + wid * 48;
  f32x4 acc[2][3];
#pragma unroll
  for (int m = 0; m < 2; m++)
#pragma unroll
    for (int n = 0; n < 3; n++) acc[m][n] = (f32x4){0.f, 0.f, 0.f, 0.f};
  const bf16_t* wb = w2b + (size_t)(ncol0 + lr) * 1376;
#pragma unroll
  for (int kk = 0; kk < 43; kk++) {
    int k0 = kk * 32 + q * 8;
    bf16x8 bfr[3];
#pragma unroll
    for (int n = 0; n < 3; n++)
      bfr[n] = *(const bf16x8*)(wb + (size_t)(n * 16) * 1376 + k0);
    bf16x8 a[2];
    if (k0 < 1368) {
      int t = k0 / 152, c0 = k0 - t * 152;
      int dy = t / 3, dxp1 = t - dy * 3;
#pragma unroll
      for (int m = 0; m < 2; m++)
        a[m] = *(const bf16x8*)(t2 + (dy * 34 + m * 16 + lr + dxp1) * 156 + c0);
    } else {
      a[0] = bzero8();
      a[1] = bzero8();
    }
#pragma unroll
    for (int n = 0; n < 3; n++)
#pragma unroll
      for (int m = 0; m < 2; m++) acc[m][n] = mfma16(a[m], bfr[n], acc[m][n]);
  }
#pragma unroll
  for (int n = 0; n < 3; n++) {
    int col = ncol0 + n * 16 + lr;
    if (col < 342) {
#pragma unroll
      for (int m = 0; m < 2; m++)
#pragma unroll
        for (int i = 0; i < 4; i++) {
          int p = (b << 12) + y * 64 + xh * 32 + m * 16 + q * 4 + i;
          offs[(size_t)p * 344 + col] = acc[m][n][i];
        }
    }
  }
}

// ---------------- S3a: deform sampler -> samp [npix][1440] bf16 (k = t*160 + g*8 + cg, pads 0) ----------------
// one thread = one (pixel, tap, group) sample; no LDS, no barriers, max TLP.
__global__ __launch_bounds__(256, 8) void s3a_sample(const bf16_t* __restrict__ out1,
                                                     const float* __restrict__ offs,
                                                     bf16_t* __restrict__ samp) {
  int task = blockIdx.x * 256 + threadIdx.x;
  int lp = task / 171, s = task - lp * 171;
  int t = s / 19, g = s - t * 19;
  int b = lp >> 12, y = (lp >> 6) & 63, xc = lp & 63;
  int ky = t / 3, kx = t - ky * 3;
  float2 ov = *(const float2*)(offs + (size_t)lp * 344 + g * 18 + t * 2);
  float ys = (float)(y - 1 + ky) + ov.x;
  float xs = (float)(xc - 1 + kx) + ov.y;
  float y0f = floorf(ys), x0f = floorf(xs);
  float wy = ys - y0f, wx = xs - x0f;
  int y0 = (int)y0f, x0 = (int)x0f;
  int y1 = y0 + 1, x1 = x0 + 1;
  int y0c = min(max(y0, 0), 63), x0c = min(max(x0, 0), 63);
  int y1c = min(max(y1, 0), 63), x1c = min(max(x1, 0), 63);
  float vy0 = (y0 == y0c) ? 1.f : 0.f;
  float vy1 = (y1 == y1c) ? 1.f : 0.f;
  float vx0 = (x0 == x0c) ? 1.f : 0.f;
  float vx1 = (x1 == x1c) ? 1.f : 0.f;
  float w00 = (1.f - wy) * (1.f - wx) * vy0 * vx0;
  float w01 = (1.f - wy) * wx * vy0 * vx1;
  float w10 = wy * (1.f - wx) * vy1 * vx0;
  float w11 = wy * wx * vy1 * vx1;
  const bf16_t* bg = out1 + (((size_t)b << 12) * 152) + g * 8;
  bf16x8 c00 = *(const bf16x8*)(bg + (size_t)(y0c * 64 + x0c) * 152);
  bf16x8 c01 = *(const bf16x8*)(bg + (size_t)(y0c * 64 + x1c) * 152);
  bf16x8 c10 = *(const bf16x8*)(bg + (size_t)(y1c * 64 + x0c) * 152);
  bf16x8 c11 = *(const bf16x8*)(bg + (size_t)(y1c * 64 + x1c) * 152);
  bf16x8 o;
#pragma unroll
  for (int i = 0; i < 8; i++) {
    float f = w00 * (float)c00[i];
    f = fmaf(w01, (float)c01[i], f);
    f = fmaf(w10, (float)c10[i], f);
    f = fmaf(w11, (float)c11[i], f);
    o[i] = (bf16_t)f;
  }
  *(bf16x8*)(samp + (size_t)lp * 1440 + t * 160 + g * 8) = o;
  if (g == 18) *(bf16x8*)(samp + (size_t)lp * 1440 + t * 160 + 152) = bzero8();
}

// ---------------- S3b: GEMM (M=16384, N=152->192, K=1440) + relu + bn2 -> a2 NHWC bf16 ----------------
// s2-style: M-tile 32, 256 thr = 4 waves x (2m x 3n); per-tap A chunk [32][168] in LDS,
// double-buffered (21.5 KB); 9 taps fully unrolled; B streamed from L2 in unrolled body.
__global__ __launch_bounds__(256, 4) void s3b_gemm(const bf16_t* __restrict__ samp,
                                                   const bf16_t* __restrict__ wdb,
                                                   const float* __restrict__ bnc,
                                                   bf16_t* __restrict__ a2) {
  __shared__ bf16_t at[2][32 * 168];  // 2 x 10752 B
  int tid = threadIdx.x;
  int row0 = blockIdx.x * 32;
  int wid = tid >> 6, lane = tid & 63, q = lane >> 4, lr = lane & 15;
  f32x4 acc[2][3];
#pragma unroll
  for (int m = 0; m < 2; m++)
#pragma unroll
    for (int n = 0; n < 3; n++) acc[m][n] = (f32x4){0.f, 0.f, 0.f, 0.f};
  const bf16_t* wb = wdb + (size_t)(wid * 48 + lr) * 1440;
  const bf16_t* arow = samp + (size_t)row0 * 1440;

#define STAGE(T, BUF)                                                        \
  for (int task = tid; task < 640; task += 256) {                            \
    int r = task / 20, c8 = task - r * 20;                                   \
    *(bf16x8*)(at[BUF] + r * 168 + c8 * 8) =                                 \
        *(const bf16x8*)(arow + (size_t)r * 1440 + (T)*160 + c8 * 8);        \
  }

#define TAP(T, BUF)                                                          \
  {                                                                          \
    if ((T) < 8) STAGE((T) + 1, (BUF) ^ 1)                                   \
    _Pragma("unroll") for (int kk = 0; kk < 5; kk++) {                       \
      int k0 = kk * 32 + q * 8;                                              \
      bf16x8 a0 = *(const bf16x8*)(at[BUF] + lr * 168 + k0);                 \
      bf16x8 a1 = *(const bf16x8*)(at[BUF] + (16 + lr) * 168 + k0);          \
      _Pragma("unroll") for (int n = 0; n < 3; n++) {                        \
        bf16x8 bf =                                                          \
            *(const bf16x8*)(wb + (size_t)(n * 16) * 1440 + (T)*160 + k0);   \
        acc[0][n] = mfma16(a0, bf, acc[0][n]);                               \
        acc[1][n] = mfma16(a1, bf, acc[1][n]);                               \
      }                                                                      \
    }                                                                        \
    __syncthreads();                                                         \
  }

  STAGE(0, 0)
  __syncthreads();
  TAP(0, 0)
  TAP(1, 1)
  TAP(2, 0)
  TAP(3, 1)
  TAP(4, 0)
  TAP(5, 1)
  TAP(6, 0)
  TAP(7, 1)
  TAP(8, 0)
#undef TAP
#undef STAGE

#pragma unroll
  for (int n = 0; n < 3; n++) {
    int oc = wid * 48 + n * 16 + lr;
    if (oc < 152) {
      float inv = bnc[304 + oc], beta = bnc[456 + oc];
#pragma unroll
      for (int m = 0; m < 2; m++)
#pragma unroll
        for (int i = 0; i < 4; i++) {
          int p = row0 + m * 16 + q * 4 + i;
          float v = fmaxf(acc[m][n][i], 0.f) * inv + beta;
          a2[(size_t)p * 152 + oc] = (bf16_t)v;
        }
    }
  }
}

// ---------------- S4: conv3 1x1 (K=152->160, N=608->640) + bn3 + residual + relu -> out NCHW fp32 ----------------
__global__ __launch_bounds__(256) void s4_conv3(const bf16_t* __restrict__ a2,
                                                const bf16_t* __restrict__ w3b,
                                                const float* __restrict__ bnc,
                                                const float* __restrict__ x,
                                                float* __restrict__ out) {
  int tid = threadIdx.x;
  int wid = tid >> 6, lane = tid & 63, q = lane >> 4, lr = lane & 15;
  int p0 = blockIdx.x * 16;
  int b = p0 >> 12, sp0 = p0 & 4095;
  f32x4 acc[10];
#pragma unroll
  for (int n = 0; n < 10; n++) acc[n] = (f32x4){0.f, 0.f, 0.f, 0.f};
  for (int kk = 0; kk < 5; kk++) {
    int k0 = kk * 32 + q * 8;
    bf16x8 a = (k0 < 152) ? *(const bf16x8*)(a2 + (size_t)(p0 + lr) * 152 + k0) : bzero8();
#pragma unroll
    for (int n = 0; n < 10; n++) {
      bf16x8 bf = *(const bf16x8*)(w3b + (size_t)(wid * 160 + n * 16 + lr) * 160 + k0);
      acc[n] = mfma16(a, bf, acc[n]);
    }
  }
#pragma unroll
  for (int n = 0; n < 10; n++) {
    int oc = wid * 160 + n * 16 + lr;
    if (oc < 608) {
      float inv = bnc[608 + oc], beta = bnc[1216 + oc];
      size_t gi = (((size_t)(b * 608 + oc)) << 12) + sp0 + q * 4;
      f32x4 xr = *(const f32x4*)(x + gi);
      f32x4 o;
#pragma unroll
      for (int i = 0; i < 4; i++) o[i] = fmaxf(acc[n][i] * inv + beta + xr[i], 0.f);
      *(f32x4*)(out + gi) = o;
    }
  }
}

extern "C" void kernel_launch(void* const* d_in, const int* in_sizes, int n_in,
                              void* d_out, int out_size, void* d_ws, size_t ws_size,
                              hipStream_t stream) {
  const float* x = (const float*)d_in[0];
  const float* w1 = (const float*)d_in[1];
  const float* w2 = (const float*)d_in[2];
  const float* wd = (const float*)d_in[3];
  const float* w3 = (const float*)d_in[4];
  const float* g1 = (const float*)d_in[5];
  const float* b1 = (const float*)d_in[6];
  const float* m1 = (const float*)d_in[7];
  const float* v1 = (const float*)d_in[8];
  const float* g2 = (const float*)d_in[9];
  const float* b2 = (const float*)d_in[10];
  const float* m2 = (const float*)d_in[11];
  const float* v2 = (const float*)d_in[12];
  const float* g3 = (const float*)d_in[13];
  const float* b3 = (const float*)d_in[14];
  const float* m3 = (const float*)d_in[15];
  const float* v3 = (const float*)d_in[16];

  char* ws = (char*)d_ws;
  bf16_t* w1b = (bf16_t*)(ws + 0);          // 194560
  bf16_t* w2b = (bf16_t*)(ws + 194560);     // 1056768 -> 1251328
  bf16_t* wdb = (bf16_t*)(ws + 1251328);    // 552960  -> 1804288
  bf16_t* w3b = (bf16_t*)(ws + 1804288);    // 204800  -> 2009088
  float* bnc = (float*)(ws + 2009088);      // 7296    -> 2016384
  bf16_t* out1 = (bf16_t*)(ws + 2016384);   // 4980736 -> 6997120
  float* offs = (float*)(ws + 6997120);     // 22544384 -> 29541504
  bf16_t* samp = (bf16_t*)(ws + 29541504);  // 16384*1440*2 = 47185920 -> 76727424
  bf16_t* a2 = (bf16_t*)(ws + 2016384);     // aliases out1 (dead after s3a)
  float* out = (float*)d_out;

  prep_weights<<<3924, 256, 0, stream>>>(w1, w2, wd, w3, w1b, w2b, wdb, w3b);
  prep_bn<<<1, 640, 0, stream>>>(g1, b1, m1, v1, g2, b2, m2, v2, g3, b3, m3, v3, bnc);
  s1_conv1<<<512, 256, 0, stream>>>(x, w1b, bnc, out1);
  s2_offs<<<1024, 256, 0, stream>>>(out1, w2b, offs);
  s3a_sample<<<10944, 256, 0, stream>>>(out1, offs, samp);
  s3b_gemm<<<512, 256, 0, stream>>>(samp, wdb, bnc, a2);
  s4_conv3<<<1024, 256, 0, stream>>>(a2, w3b, bnc, x, out);
}

// Round 13
// 178.415 us; speedup vs baseline: 1.0096x; 1.0096x over previous
//
#include <hip/hip_runtime.h>

#define EPSV 1e-5f

typedef __bf16 bf16_t;
typedef __bf16 bf16x8 __attribute__((ext_vector_type(8)));
typedef float f32x4 __attribute__((ext_vector_type(4)));

__device__ inline bf16x8 bzero8() {
  bf16x8 z;
#pragma unroll
  for (int i = 0; i < 8; i++) z[i] = (bf16_t)0.f;
  return z;
}

__device__ inline f32x4 mfma16(bf16x8 a, bf16x8 b, f32x4 c) {
  return __builtin_amdgcn_mfma_f32_16x16x32_bf16(a, b, c, 0, 0, 0);
}

// ---------------- weight prep: fp32 -> bf16, padded + reordered ----------------
// w1b [160][608]        (row=oc, k=ic)               oc>=152 zero
// w2b [384][1376]       (row=oc, k=tap*152+ic)       pads zero
// wdb [192][1440]       (row=o,  k=tap*160+ic)       pads zero (per-tap slice padded to 160)
// w3b [640][160]        (row=oc, k=ic)               k>=152 / oc>=608 zero
#define W1E (160 * 608)
#define W2E (384 * 1376)
#define WDE (192 * 1440)
#define W3E (640 * 160)

__global__ __launch_bounds__(256) void prep_weights(
    const float* __restrict__ w1, const float* __restrict__ w2,
    const float* __restrict__ wd, const float* __restrict__ w3,
    bf16_t* __restrict__ w1b, bf16_t* __restrict__ w2b,
    bf16_t* __restrict__ wdb, bf16_t* __restrict__ w3b) {
  int i = blockIdx.x * 256 + threadIdx.x;
  float v = 0.f;
  if (i < W1E) {
    int oc = i / 608, ic = i % 608;
    if (oc < 152) v = w1[oc * 608 + ic];
    w1b[i] = (bf16_t)v;
  } else if (i < W1E + W2E) {
    int j = i - W1E;
    int oc = j / 1376, k = j % 1376;
    if (oc < 342 && k < 1368) {
      int t = k / 152, ic = k % 152;
      v = w2[(oc * 152 + ic) * 9 + t];
    }
    w2b[j] = (bf16_t)v;
  } else if (i < W1E + W2E + WDE) {
    int j = i - W1E - W2E;
    int o = j / 1440, k = j % 1440;
    int t = k / 160, ic = k % 160;
    if (o < 152 && ic < 152) v = wd[(o * 152 + ic) * 9 + t];
    wdb[j] = (bf16_t)v;
  } else if (i < W1E + W2E + WDE + W3E) {
    int j = i - W1E - W2E - WDE;
    int oc = j / 160, ic = j % 160;
    if (oc < 608 && ic < 152) v = w3[oc * 152 + ic];
    w3b[j] = (bf16_t)v;
  }
}

// bnc layout: [0,152) inv1, [152,304) beta1, [304,456) inv2, [456,608) beta2,
//             [608,1216) inv3, [1216,1824) beta3
__global__ void prep_bn(const float* g1, const float* b1, const float* m1, const float* v1,
                        const float* g2, const float* b2, const float* m2, const float* v2,
                        const float* g3, const float* b3, const float* m3, const float* v3,
                        float* __restrict__ bnc) {
  int i = threadIdx.x;
  if (i < 152) {
    float inv = g1[i] / sqrtf(v1[i] + EPSV);
    bnc[i] = inv;
    bnc[152 + i] = b1[i] - m1[i] * inv;
    float inv2 = g2[i] / sqrtf(v2[i] + EPSV);
    bnc[304 + i] = inv2;
    bnc[456 + i] = b2[i] - m2[i] * inv2;
  }
  if (i < 608) {
    float inv3 = g3[i] / sqrtf(v3[i] + EPSV);
    bnc[608 + i] = inv3;
    bnc[1216 + i] = b3[i] - m3[i] * inv3;
  }
}

// ---------------- S1: conv1 1x1 (K=608,N=152) + relu + bn1 -> out1 NHWC bf16 ----------------
__global__ __launch_bounds__(256) void s1_conv1(const float* __restrict__ x,
                                                const bf16_t* __restrict__ w1b,
                                                const float* __restrict__ bnc,
                                                bf16_t* __restrict__ out1) {
  __shared__ bf16_t t1[32 * 616];  // 38.5 KB
  int tid = threadIdx.x;
  int px0 = blockIdx.x * 32;
  int b = px0 >> 12, sp0 = px0 & 4095;
  for (int task = tid; task < 608 * 8; task += 256) {
    int c = task >> 3, i4 = task & 7;
    f32x4 v = *(const f32x4*)(x + (((size_t)(b * 608 + c)) << 12) + sp0 + i4 * 4);
#pragma unroll
    for (int i = 0; i < 4; i++) t1[(i4 * 4 + i) * 616 + c] = (bf16_t)v[i];
  }
  __syncthreads();
  int wid = tid >> 6, lane = tid & 63, q = lane >> 4, lr = lane & 15;
  int mw = wid & 1, nw = wid >> 1;  // 2M x 2N
  f32x4 acc[5];
#pragma unroll
  for (int n = 0; n < 5; n++) acc[n] = (f32x4){0.f, 0.f, 0.f, 0.f};
  for (int kk = 0; kk < 19; kk++) {
    int k0 = kk * 32 + q * 8;
    bf16x8 a = *(const bf16x8*)(t1 + (mw * 16 + lr) * 616 + k0);
#pragma unroll
    for (int n = 0; n < 5; n++) {
      bf16x8 bf = *(const bf16x8*)(w1b + (nw * 80 + n * 16 + lr) * 608 + k0);
      acc[n] = mfma16(a, bf, acc[n]);
    }
  }
#pragma unroll
  for (int n = 0; n < 5; n++) {
    int oc = nw * 80 + n * 16 + lr;
    if (oc < 152) {
      float inv = bnc[oc], beta = bnc[152 + oc];
#pragma unroll
      for (int i = 0; i < 4; i++) {
        int p = px0 + mw * 16 + q * 4 + i;
        float v = fmaxf(acc[n][i], 0.f) * inv + beta;
        out1[(size_t)p * 152 + oc] = (bf16_t)v;
      }
    }
  }
}

// ---------------- S2: offset conv 3x3 (K=1368->1376, N=342->384) -> offs fp32 [pix][col] ----------------
__global__ __launch_bounds__(256, 4) void s2_offs(const bf16_t* __restrict__ out1,
                                                  const bf16_t* __restrict__ w2b,
                                                  float* __restrict__ offs) {
  __shared__ bf16_t t2[3 * 34 * 156];  // 31.8 KB
  int tid = threadIdx.x;
  int nh = blockIdx.x & 1;
  int rest = blockIdx.x >> 1;
  int xh = rest & 1, y = (rest >> 1) & 63, b = rest >> 7;
  const bf16_t* ob = out1 + (((size_t)b) << 12) * 152;
  int x0 = xh * 32 - 1;
  for (int task = tid; task < 3 * 34 * 19; task += 256) {
    int j = task / 646, r = task % 646;
    int xi = r / 19, cb = r % 19;
    int yy = y + j - 1, xx = x0 + xi;
    bf16x8 v = bzero8();
    if (yy >= 0 && yy < 64 && xx >= 0 && xx < 64)
      v = *(const bf16x8*)(ob + (size_t)(yy * 64 + xx) * 152 + cb * 8);
    *(bf16x8*)(t2 + (j * 34 + xi) * 156 + cb * 8) = v;
  }
  __syncthreads();
  int wid = tid >> 6, lane = tid & 63, q = lane >> 4, lr = lane & 15;
  int ncol0 = nh * 192 + wid * 48;
  f32x4 acc[2][3];
#pragma unroll
  for (int m = 0; m < 2; m++)
#pragma unroll
    for (int n = 0; n < 3; n++) acc[m][n] = (f32x4){0.f, 0.f, 0.f, 0.f};
  const bf16_t* wb = w2b + (size_t)(ncol0 + lr) * 1376;
#pragma unroll
  for (int kk = 0; kk < 43; kk++) {
    int k0 = kk * 32 + q * 8;
    bf16x8 bfr[3];
#pragma unroll
    for (int n = 0; n < 3; n++)
      bfr[n] = *(const bf16x8*)(wb + (size_t)(n * 16) * 1376 + k0);
    bf16x8 a[2];
    if (k0 < 1368) {
      int t = k0 / 152, c0 = k0 - t * 152;
      int dy = t / 3, dxp1 = t - dy * 3;
#pragma unroll
      for (int m = 0; m < 2; m++)
        a[m] = *(const bf16x8*)(t2 + (dy * 34 + m * 16 + lr + dxp1) * 156 + c0);
    } else {
      a[0] = bzero8();
      a[1] = bzero8();
    }
#pragma unroll
    for (int n = 0; n < 3; n++)
#pragma unroll
      for (int m = 0; m < 2; m++) acc[m][n] = mfma16(a[m], bfr[n], acc[m][n]);
  }
#pragma unroll
  for (int n = 0; n < 3; n++) {
    int col = ncol0 + n * 16 + lr;
    if (col < 342) {
#pragma unroll
      for (int m = 0; m < 2; m++)
#pragma unroll
        for (int i = 0; i < 4; i++) {
          int p = (b << 12) + y * 64 + xh * 32 + m * 16 + q * 4 + i;
          offs[(size_t)p * 344 + col] = acc[m][n][i];
        }
    }
  }
}

// ---------------- S3a: deform sampler -> samp [npix][1440] bf16 (k = t*160 + g*8 + cg, pads 0) ----------------
// one thread = one (pixel, tap, group) sample; no LDS, no barriers, max TLP.
__global__ __launch_bounds__(256, 8) void s3a_sample(const bf16_t* __restrict__ out1,
                                                     const float* __restrict__ offs,
                                                     bf16_t* __restrict__ samp) {
  int task = blockIdx.x * 256 + threadIdx.x;
  int lp = task / 171, s = task - lp * 171;
  int t = s / 19, g = s - t * 19;
  int b = lp >> 12, y = (lp >> 6) & 63, xc = lp & 63;
  int ky = t / 3, kx = t - ky * 3;
  float2 ov = *(const float2*)(offs + (size_t)lp * 344 + g * 18 + t * 2);
  float ys = (float)(y - 1 + ky) + ov.x;
  float xs = (float)(xc - 1 + kx) + ov.y;
  float y0f = floorf(ys), x0f = floorf(xs);
  float wy = ys - y0f, wx = xs - x0f;
  int y0 = (int)y0f, x0 = (int)x0f;
  int y1 = y0 + 1, x1 = x0 + 1;
  int y0c = min(max(y0, 0), 63), x0c = min(max(x0, 0), 63);
  int y1c = min(max(y1, 0), 63), x1c = min(max(x1, 0), 63);
  float vy0 = (y0 == y0c) ? 1.f : 0.f;
  float vy1 = (y1 == y1c) ? 1.f : 0.f;
  float vx0 = (x0 == x0c) ? 1.f : 0.f;
  float vx1 = (x1 == x1c) ? 1.f : 0.f;
  float w00 = (1.f - wy) * (1.f - wx) * vy0 * vx0;
  float w01 = (1.f - wy) * wx * vy0 * vx1;
  float w10 = wy * (1.f - wx) * vy1 * vx0;
  float w11 = wy * wx * vy1 * vx1;
  const bf16_t* bg = out1 + (((size_t)b << 12) * 152) + g * 8;
  bf16x8 c00 = *(const bf16x8*)(bg + (size_t)(y0c * 64 + x0c) * 152);
  bf16x8 c01 = *(const bf16x8*)(bg + (size_t)(y0c * 64 + x1c) * 152);
  bf16x8 c10 = *(const bf16x8*)(bg + (size_t)(y1c * 64 + x0c) * 152);
  bf16x8 c11 = *(const bf16x8*)(bg + (size_t)(y1c * 64 + x1c) * 152);
  bf16x8 o;
#pragma unroll
  for (int i = 0; i < 8; i++) {
    float f = w00 * (float)c00[i];
    f = fmaf(w01, (float)c01[i], f);
    f = fmaf(w10, (float)c10[i], f);
    f = fmaf(w11, (float)c11[i], f);
    o[i] = (bf16_t)f;
  }
  *(bf16x8*)(samp + (size_t)lp * 1440 + t * 160 + g * 8) = o;
  if (g == 18) *(bf16x8*)(samp + (size_t)lp * 1440 + t * 160 + 152) = bzero8();
}

// ---------------- S3b: GEMM (M=16384, N=152->192, K=1440) + relu + bn2 -> a2 NHWC bf16 ----------------
// N-split: block = 32 px x 96 cols (nh = bid&1), grid 1024 -> 4 blocks/CU (~50% occ).
// 4 waves = 2m x 2n (3 frags each); per-tap A chunk [32][168] LDS double-buffered;
// 9 taps fully unrolled; B streamed from L2; samp re-read is L3-hit.
__global__ __launch_bounds__(256, 4) void s3b_gemm(const bf16_t* __restrict__ samp,
                                                   const bf16_t* __restrict__ wdb,
                                                   const float* __restrict__ bnc,
                                                   bf16_t* __restrict__ a2) {
  __shared__ bf16_t at[2][32 * 168];  // 2 x 10752 B
  int tid = threadIdx.x;
  int nh = blockIdx.x & 1;
  int row0 = (blockIdx.x >> 1) * 32;
  int wid = tid >> 6, lane = tid & 63, q = lane >> 4, lr = lane & 15;
  int mw = wid & 1, nw = wid >> 1;
  int col0 = nh * 96 + nw * 48;
  f32x4 acc[3];
#pragma unroll
  for (int n = 0; n < 3; n++) acc[n] = (f32x4){0.f, 0.f, 0.f, 0.f};
  const bf16_t* wb = wdb + (size_t)(col0 + lr) * 1440;
  const bf16_t* arow = samp + (size_t)row0 * 1440;

#define STAGE(T, BUF)                                                        \
  for (int task = tid; task < 640; task += 256) {                            \
    int r = task / 20, c8 = task - r * 20;                                   \
    *(bf16x8*)(at[BUF] + r * 168 + c8 * 8) =                                 \
        *(const bf16x8*)(arow + (size_t)r * 1440 + (T)*160 + c8 * 8);        \
  }

#define TAP(T, BUF)                                                          \
  {                                                                          \
    if ((T) < 8) STAGE((T) + 1, (BUF) ^ 1)                                   \
    _Pragma("unroll") for (int kk = 0; kk < 5; kk++) {                       \
      int k0 = kk * 32 + q * 8;                                              \
      bf16x8 a = *(const bf16x8*)(at[BUF] + (mw * 16 + lr) * 168 + k0);      \
      _Pragma("unroll") for (int n = 0; n < 3; n++) {                        \
        bf16x8 bf =                                                          \
            *(const bf16x8*)(wb + (size_t)(n * 16) * 1440 + (T)*160 + k0);   \
        acc[n] = mfma16(a, bf, acc[n]);                                      \
      }                                                                      \
    }                                                                        \
    __syncthreads();                                                         \
  }

  STAGE(0, 0)
  __syncthreads();
  TAP(0, 0)
  TAP(1, 1)
  TAP(2, 0)
  TAP(3, 1)
  TAP(4, 0)
  TAP(5, 1)
  TAP(6, 0)
  TAP(7, 1)
  TAP(8, 0)
#undef TAP
#undef STAGE

#pragma unroll
  for (int n = 0; n < 3; n++) {
    int oc = col0 + n * 16 + lr;
    if (oc < 152) {
      float inv = bnc[304 + oc], beta = bnc[456 + oc];
#pragma unroll
      for (int i = 0; i < 4; i++) {
        int p = row0 + mw * 16 + q * 4 + i;
        float v = fmaxf(acc[n][i], 0.f) * inv + beta;
        a2[(size_t)p * 152 + oc] = (bf16_t)v;
      }
    }
  }
}

// ---------------- S4: conv3 1x1 (K=152->160, N=608->640) + bn3 + residual + relu -> out NCHW fp32 ----------------
__global__ __launch_bounds__(256) void s4_conv3(const bf16_t* __restrict__ a2,
                                                const bf16_t* __restrict__ w3b,
                                                const float* __restrict__ bnc,
                                                const float* __restrict__ x,
                                                float* __restrict__ out) {
  int tid = threadIdx.x;
  int wid = tid >> 6, lane = tid & 63, q = lane >> 4, lr = lane & 15;
  int p0 = blockIdx.x * 16;
  int b = p0 >> 12, sp0 = p0 & 4095;
  f32x4 acc[10];
#pragma unroll
  for (int n = 0; n < 10; n++) acc[n] = (f32x4){0.f, 0.f, 0.f, 0.f};
  for (int kk = 0; kk < 5; kk++) {
    int k0 = kk * 32 + q * 8;
    bf16x8 a = (k0 < 152) ? *(const bf16x8*)(a2 + (size_t)(p0 + lr) * 152 + k0) : bzero8();
#pragma unroll
    for (int n = 0; n < 10; n++) {
      bf16x8 bf = *(const bf16x8*)(w3b + (size_t)(wid * 160 + n * 16 + lr) * 160 + k0);
      acc[n] = mfma16(a, bf, acc[n]);
    }
  }
#pragma unroll
  for (int n = 0; n < 10; n++) {
    int oc = wid * 160 + n * 16 + lr;
    if (oc < 608) {
      float inv = bnc[608 + oc], beta = bnc[1216 + oc];
      size_t gi = (((size_t)(b * 608 + oc)) << 12) + sp0 + q * 4;
      f32x4 xr = *(const f32x4*)(x + gi);
      f32x4 o;
#pragma unroll
      for (int i = 0; i < 4; i++) o[i] = fmaxf(acc[n][i] * inv + beta + xr[i], 0.f);
      *(f32x4*)(out + gi) = o;
    }
  }
}

extern "C" void kernel_launch(void* const* d_in, const int* in_sizes, int n_in,
                              void* d_out, int out_size, void* d_ws, size_t ws_size,
                              hipStream_t stream) {
  const float* x = (const float*)d_in[0];
  const float* w1 = (const float*)d_in[1];
  const float* w2 = (const float*)d_in[2];
  const float* wd = (const float*)d_in[3];
  const float* w3 = (const float*)d_in[4];
  const float* g1 = (const float*)d_in[5];
  const float* b1 = (const float*)d_in[6];
  const float* m1 = (const float*)d_in[7];
  const float* v1 = (const float*)d_in[8];
  const float* g2 = (const float*)d_in[9];
  const float* b2 = (const float*)d_in[10];
  const float* m2 = (const float*)d_in[11];
  const float* v2 = (const float*)d_in[12];
  const float* g3 = (const float*)d_in[13];
  const float* b3 = (const float*)d_in[14];
  const float* m3 = (const float*)d_in[15];
  const float* v3 = (const float*)d_in[16];

  char* ws = (char*)d_ws;
  bf16_t* w1b = (bf16_t*)(ws + 0);          // 194560
  bf16_t* w2b = (bf16_t*)(ws + 194560);     // 1056768 -> 1251328
  bf16_t* wdb = (bf16_t*)(ws + 1251328);    // 552960  -> 1804288
  bf16_t* w3b = (bf16_t*)(ws + 1804288);    // 204800  -> 2009088
  float* bnc = (float*)(ws + 2009088);      // 7296    -> 2016384
  bf16_t* out1 = (bf16_t*)(ws + 2016384);   // 4980736 -> 6997120
  float* offs = (float*)(ws + 6997120);     // 22544384 -> 29541504
  bf16_t* samp = (bf16_t*)(ws + 29541504);  // 16384*1440*2 = 47185920 -> 76727424
  bf16_t* a2 = (bf16_t*)(ws + 2016384);     // aliases out1 (dead after s3a)
  float* out = (float*)d_out;

  prep_weights<<<3924, 256, 0, stream>>>(w1, w2, wd, w3, w1b, w2b, wdb, w3b);
  prep_bn<<<1, 640, 0, stream>>>(g1, b1, m1, v1, g2, b2, m2, v2, g3, b3, m3, v3, bnc);
  s1_conv1<<<512, 256, 0, stream>>>(x, w1b, bnc, out1);
  s2_offs<<<1024, 256, 0, stream>>>(out1, w2b, offs);
  s3a_sample<<<10944, 256, 0, stream>>>(out1, offs, samp);
  s3b_gemm<<<1024, 256, 0, stream>>>(samp, wdb, bnc, a2);
  s4_conv3<<<1024, 256, 0, stream>>>(a2, w3b, bnc, x, out);
}

// Round 14
// 166.651 us; speedup vs baseline: 1.0809x; 1.0706x over previous
//
#include <hip/hip_runtime.h>

#define EPSV 1e-5f

typedef __bf16 bf16_t;
typedef __bf16 bf16x8 __attribute__((ext_vector_type(8)));
typedef float f32x4 __attribute__((ext_vector_type(4)));

#define GLOAD_LDS(g, l)                                             \
  __builtin_amdgcn_global_load_lds(                                 \
      (const __attribute__((address_space(1))) void*)(g),           \
      (__attribute__((address_space(3))) void*)(l), 16, 0, 0)

__device__ inline bf16x8 bzero8() {
  bf16x8 z;
#pragma unroll
  for (int i = 0; i < 8; i++) z[i] = (bf16_t)0.f;
  return z;
}

__device__ inline f32x4 mfma16(bf16x8 a, bf16x8 b, f32x4 c) {
  return __builtin_amdgcn_mfma_f32_16x16x32_bf16(a, b, c, 0, 0, 0);
}

// ---------------- weight prep: fp32 -> bf16, padded + reordered ----------------
// w1b [160][608]   (row=oc, k=ic)          oc>=152 zero
// w2b [384][1440]  (row=oc, k=tap*160+ic)  pads zero
// wdb [192][1440]  (row=o,  k=tap*160+ic)  pads zero
// w3b [640][160]   (row=oc, k=ic)          pads zero
#define W1E (160 * 608)
#define W2E (384 * 1440)
#define WDE (192 * 1440)
#define W3E (640 * 160)

__global__ __launch_bounds__(256) void prep_weights(
    const float* __restrict__ w1, const float* __restrict__ w2,
    const float* __restrict__ wd, const float* __restrict__ w3,
    bf16_t* __restrict__ w1b, bf16_t* __restrict__ w2b,
    bf16_t* __restrict__ wdb, bf16_t* __restrict__ w3b) {
  int i = blockIdx.x * 256 + threadIdx.x;
  float v = 0.f;
  if (i < W1E) {
    int oc = i / 608, ic = i % 608;
    if (oc < 152) v = w1[oc * 608 + ic];
    w1b[i] = (bf16_t)v;
  } else if (i < W1E + W2E) {
    int j = i - W1E;
    int oc = j / 1440, k = j % 1440;
    int t = k / 160, ic = k % 160;
    if (oc < 342 && ic < 152) v = w2[(oc * 152 + ic) * 9 + t];
    w2b[j] = (bf16_t)v;
  } else if (i < W1E + W2E + WDE) {
    int j = i - W1E - W2E;
    int o = j / 1440, k = j % 1440;
    int t = k / 160, ic = k % 160;
    if (o < 152 && ic < 152) v = wd[(o * 152 + ic) * 9 + t];
    wdb[j] = (bf16_t)v;
  } else if (i < W1E + W2E + WDE + W3E) {
    int j = i - W1E - W2E - WDE;
    int oc = j / 160, ic = j % 160;
    if (oc < 608 && ic < 152) v = w3[oc * 152 + ic];
    w3b[j] = (bf16_t)v;
  }
}

// bnc layout: [0,152) inv1, [152,304) beta1, [304,456) inv2, [456,608) beta2,
//             [608,1216) inv3, [1216,1824) beta3
__global__ void prep_bn(const float* g1, const float* b1, const float* m1, const float* v1,
                        const float* g2, const float* b2, const float* m2, const float* v2,
                        const float* g3, const float* b3, const float* m3, const float* v3,
                        float* __restrict__ bnc) {
  int i = threadIdx.x;
  if (i < 152) {
    float inv = g1[i] / sqrtf(v1[i] + EPSV);
    bnc[i] = inv;
    bnc[152 + i] = b1[i] - m1[i] * inv;
    float inv2 = g2[i] / sqrtf(v2[i] + EPSV);
    bnc[304 + i] = inv2;
    bnc[456 + i] = b2[i] - m2[i] * inv2;
  }
  if (i < 608) {
    float inv3 = g3[i] / sqrtf(v3[i] + EPSV);
    bnc[608 + i] = inv3;
    bnc[1216 + i] = b3[i] - m3[i] * inv3;
  }
}

// ---------------- S1: conv1 1x1 + relu + bn1 -> out1p [4][66][66][152] bf16 (zero ring) ----------------
__global__ __launch_bounds__(256) void s1_conv1(const float* __restrict__ x,
                                                const bf16_t* __restrict__ w1b,
                                                const float* __restrict__ bnc,
                                                bf16_t* __restrict__ out1p) {
  __shared__ bf16_t t1[32 * 616];  // 38.5 KB
  int tid = threadIdx.x;
  int px0 = blockIdx.x * 32;
  int b = px0 >> 12, sp0 = px0 & 4095;
  for (int task = tid; task < 608 * 8; task += 256) {
    int c = task >> 3, i4 = task & 7;
    f32x4 v = *(const f32x4*)(x + (((size_t)(b * 608 + c)) << 12) + sp0 + i4 * 4);
#pragma unroll
    for (int i = 0; i < 4; i++) t1[(i4 * 4 + i) * 616 + c] = (bf16_t)v[i];
  }
  __syncthreads();
  int wid = tid >> 6, lane = tid & 63, q = lane >> 4, lr = lane & 15;
  int mw = wid & 1, nw = wid >> 1;  // 2M x 2N
  f32x4 acc[5];
#pragma unroll
  for (int n = 0; n < 5; n++) acc[n] = (f32x4){0.f, 0.f, 0.f, 0.f};
  for (int kk = 0; kk < 19; kk++) {
    int k0 = kk * 32 + q * 8;
    bf16x8 a = *(const bf16x8*)(t1 + (mw * 16 + lr) * 616 + k0);
#pragma unroll
    for (int n = 0; n < 5; n++) {
      bf16x8 bf = *(const bf16x8*)(w1b + (nw * 80 + n * 16 + lr) * 608 + k0);
      acc[n] = mfma16(a, bf, acc[n]);
    }
  }
#pragma unroll
  for (int n = 0; n < 5; n++) {
    int oc = nw * 80 + n * 16 + lr;
    if (oc < 152) {
      float inv = bnc[oc], beta = bnc[152 + oc];
#pragma unroll
      for (int i = 0; i < 4; i++) {
        int p = px0 + mw * 16 + q * 4 + i;
        int y = (p >> 6) & 63, xx = p & 63;
        float v = fmaxf(acc[n][i], 0.f) * inv + beta;
        out1p[(size_t)(b * 4356 + (y + 1) * 66 + (xx + 1)) * 152 + oc] = (bf16_t)v;
      }
    }
  }
}

// ---------------- S2: offset conv as tiled GEMM (M=16384, N=384, K=1440) -> offs fp32 ----------------
// BM=128 x BN=96 x BK=32; A = im2col of padded out1p (per-lane gather -> global_load_lds);
// B = w2b staged to LDS; 1 barrier per K-step; grid 512 = 2 blocks/CU.
__global__ __launch_bounds__(256, 4) void s2_offs(const bf16_t* __restrict__ out1p,
                                                  const bf16_t* __restrict__ w2b,
                                                  const bf16_t* __restrict__ zbuf,
                                                  float* __restrict__ offs) {
  __shared__ bf16_t At[2][128 * 32];  // 8 KB each
  __shared__ bf16_t Bt[2][96 * 32];   // 6 KB each
  int tid = threadIdx.x;
  int w = tid >> 6, l = tid & 63;
  int ct = blockIdx.x & 3;
  int p0 = (blockIdx.x >> 2) * 128;
  int c0 = ct * 96;
  int lr = l & 15, q = l >> 4;
  int mw = w & 1, nw = w >> 1;
  int rA = l >> 2, cA = l & 3;
  int b = p0 >> 12;

  f32x4 acc[4][3];
#pragma unroll
  for (int m = 0; m < 4; m++)
#pragma unroll
    for (int n = 0; n < 3; n++) acc[m][n] = (f32x4){0.f, 0.f, 0.f, 0.f};

#define S2_STAGE(KK, BUF)                                                      \
  {                                                                            \
    int kk_ = (KK);                                                            \
    int t_ = kk_ / 5;                                                          \
    int ic0_ = (kk_ - t_ * 5) * 32;                                            \
    int dy_ = t_ / 3 - 1, dx_ = t_ - (t_ / 3) * 3 - 1;                         \
    int doff_ = dy_ * 66 + dx_;                                                \
    int ic_ = ic0_ + cA * 8;                                                   \
    for (int s = w; s < 8; s += 4) {                                           \
      int px = p0 + s * 16 + rA;                                               \
      int y = (px >> 6) & 63, xx = px & 63;                                    \
      const bf16_t* g =                                                        \
          (ic_ < 152)                                                          \
              ? out1p + (size_t)(b * 4356 + (y + 1) * 66 + (xx + 1) + doff_) * \
                            152 +                                              \
                    ic_                                                        \
              : zbuf + cA * 8;                                                 \
      GLOAD_LDS(g, &At[BUF][s * 512]);                                         \
    }                                                                          \
    for (int s = w; s < 6; s += 4) {                                           \
      int col = c0 + s * 16 + rA;                                              \
      const bf16_t* g = w2b + (size_t)col * 1440 + kk_ * 32 + cA * 8;          \
      GLOAD_LDS(g, &Bt[BUF][s * 512]);                                         \
    }                                                                          \
  }

  S2_STAGE(0, 0)
  __syncthreads();
  for (int kk = 0; kk < 45; kk++) {
    int buf = kk & 1;
    if (kk < 44) S2_STAGE(kk + 1, buf ^ 1)
    bf16x8 a[4], bfr[3];
#pragma unroll
    for (int m = 0; m < 4; m++)
      a[m] = *(const bf16x8*)&At[buf][(mw * 64 + m * 16 + lr) * 32 + q * 8];
#pragma unroll
    for (int n = 0; n < 3; n++)
      bfr[n] = *(const bf16x8*)&Bt[buf][(nw * 48 + n * 16 + lr) * 32 + q * 8];
#pragma unroll
    for (int m = 0; m < 4; m++)
#pragma unroll
      for (int n = 0; n < 3; n++) acc[m][n] = mfma16(a[m], bfr[n], acc[m][n]);
    __syncthreads();
  }
#undef S2_STAGE

#pragma unroll
  for (int n = 0; n < 3; n++) {
    int col = c0 + nw * 48 + n * 16 + lr;
    if (col < 342) {
#pragma unroll
      for (int m = 0; m < 4; m++)
#pragma unroll
        for (int i = 0; i < 4; i++) {
          int px = p0 + mw * 64 + m * 16 + q * 4 + i;
          offs[(size_t)px * 344 + col] = acc[m][n][i];
        }
    }
  }
}

// ---------------- S3a: deform sampler -> samp [npix][1440] bf16 (k = t*160 + g*8, pads 0) ----------------
__global__ __launch_bounds__(256, 8) void s3a_sample(const bf16_t* __restrict__ out1p,
                                                     const float* __restrict__ offs,
                                                     bf16_t* __restrict__ samp) {
  int task = blockIdx.x * 256 + threadIdx.x;
  int lp = task / 171, s = task - lp * 171;
  int t = s / 19, g = s - t * 19;
  int b = lp >> 12, y = (lp >> 6) & 63, xc = lp & 63;
  int ky = t / 3, kx = t - ky * 3;
  float2 ov = *(const float2*)(offs + (size_t)lp * 344 + g * 18 + t * 2);
  float ys = (float)(y - 1 + ky) + ov.x;
  float xs = (float)(xc - 1 + kx) + ov.y;
  float y0f = floorf(ys), x0f = floorf(xs);
  float wy = ys - y0f, wx = xs - x0f;
  int y0 = (int)y0f, x0 = (int)x0f;
  int y1 = y0 + 1, x1 = x0 + 1;
  int y0c = min(max(y0, 0), 63), x0c = min(max(x0, 0), 63);
  int y1c = min(max(y1, 0), 63), x1c = min(max(x1, 0), 63);
  float vy0 = (y0 == y0c) ? 1.f : 0.f;
  float vy1 = (y1 == y1c) ? 1.f : 0.f;
  float vx0 = (x0 == x0c) ? 1.f : 0.f;
  float vx1 = (x1 == x1c) ? 1.f : 0.f;
  float w00 = (1.f - wy) * (1.f - wx) * vy0 * vx0;
  float w01 = (1.f - wy) * wx * vy0 * vx1;
  float w10 = wy * (1.f - wx) * vy1 * vx0;
  float w11 = wy * wx * vy1 * vx1;
  const bf16_t* bg = out1p + (size_t)(b * 4356) * 152 + g * 8;
  bf16x8 c00 = *(const bf16x8*)(bg + (size_t)((y0c + 1) * 66 + x0c + 1) * 152);
  bf16x8 c01 = *(const bf16x8*)(bg + (size_t)((y0c + 1) * 66 + x1c + 1) * 152);
  bf16x8 c10 = *(const bf16x8*)(bg + (size_t)((y1c + 1) * 66 + x0c + 1) * 152);
  bf16x8 c11 = *(const bf16x8*)(bg + (size_t)((y1c + 1) * 66 + x1c + 1) * 152);
  bf16x8 o;
#pragma unroll
  for (int i = 0; i < 8; i++) {
    float f = w00 * (float)c00[i];
    f = fmaf(w01, (float)c01[i], f);
    f = fmaf(w10, (float)c10[i], f);
    f = fmaf(w11, (float)c11[i], f);
    o[i] = (bf16_t)f;
  }
  *(bf16x8*)(samp + (size_t)lp * 1440 + t * 160 + g * 8) = o;
  if (g == 18) *(bf16x8*)(samp + (size_t)lp * 1440 + t * 160 + 152) = bzero8();
}

// ---------------- S3b: tiled GEMM (M=16384, N=192, K=1440) + relu + bn2 -> a2 NHWC bf16 ----------------
// BM=64 x BN=96 x BK=32, same template as s2 (A dense from samp); grid 512 = 2 blocks/CU.
__global__ __launch_bounds__(256, 4) void s3b_gemm(const bf16_t* __restrict__ samp,
                                                   const bf16_t* __restrict__ wdb,
                                                   const float* __restrict__ bnc,
                                                   bf16_t* __restrict__ a2) {
  __shared__ bf16_t At[2][64 * 32];  // 4 KB each
  __shared__ bf16_t Bt[2][96 * 32];  // 6 KB each
  int tid = threadIdx.x;
  int w = tid >> 6, l = tid & 63;
  int c0 = (blockIdx.x & 1) * 96;
  int p0 = (blockIdx.x >> 1) * 64;
  int lr = l & 15, q = l >> 4;
  int mw = w & 1, nw = w >> 1;
  int rA = l >> 2, cA = l & 3;

  f32x4 acc[2][3];
#pragma unroll
  for (int m = 0; m < 2; m++)
#pragma unroll
    for (int n = 0; n < 3; n++) acc[m][n] = (f32x4){0.f, 0.f, 0.f, 0.f};

#define S3_STAGE(KK, BUF)                                                     \
  {                                                                           \
    int kk_ = (KK);                                                           \
    for (int s = w; s < 4; s += 4) {                                          \
      int px = p0 + s * 16 + rA;                                              \
      const bf16_t* g = samp + (size_t)px * 1440 + kk_ * 32 + cA * 8;         \
      GLOAD_LDS(g, &At[BUF][s * 512]);                                        \
    }                                                                         \
    for (int s = w; s < 6; s += 4) {                                          \
      int col = c0 + s * 16 + rA;                                             \
      const bf16_t* g = wdb + (size_t)col * 1440 + kk_ * 32 + cA * 8;         \
      GLOAD_LDS(g, &Bt[BUF][s * 512]);                                        \
    }                                                                         \
  }

  S3_STAGE(0, 0)
  __syncthreads();
  for (int kk = 0; kk < 45; kk++) {
    int buf = kk & 1;
    if (kk < 44) S3_STAGE(kk + 1, buf ^ 1)
    bf16x8 a[2], bfr[3];
#pragma unroll
    for (int m = 0; m < 2; m++)
      a[m] = *(const bf16x8*)&At[buf][(mw * 32 + m * 16 + lr) * 32 + q * 8];
#pragma unroll
    for (int n = 0; n < 3; n++)
      bfr[n] = *(const bf16x8*)&Bt[buf][(nw * 48 + n * 16 + lr) * 32 + q * 8];
#pragma unroll
    for (int m = 0; m < 2; m++)
#pragma unroll
      for (int n = 0; n < 3; n++) acc[m][n] = mfma16(a[m], bfr[n], acc[m][n]);
    __syncthreads();
  }
#undef S3_STAGE

#pragma unroll
  for (int n = 0; n < 3; n++) {
    int oc = c0 + nw * 48 + n * 16 + lr;
    if (oc < 152) {
      float inv = bnc[304 + oc], beta = bnc[456 + oc];
#pragma unroll
      for (int m = 0; m < 2; m++)
#pragma unroll
        for (int i = 0; i < 4; i++) {
          int px = p0 + mw * 32 + m * 16 + q * 4 + i;
          float v = fmaxf(acc[m][n][i], 0.f) * inv + beta;
          a2[(size_t)px * 152 + oc] = (bf16_t)v;
        }
    }
  }
}

// ---------------- S4: conv3 1x1 (K=152->160, N=608->640) + bn3 + residual + relu -> out NCHW fp32 ----------------
__global__ __launch_bounds__(256) void s4_conv3(const bf16_t* __restrict__ a2,
                                                const bf16_t* __restrict__ w3b,
                                                const float* __restrict__ bnc,
                                                const float* __restrict__ x,
                                                float* __restrict__ out) {
  int tid = threadIdx.x;
  int wid = tid >> 6, lane = tid & 63, q = lane >> 4, lr = lane & 15;
  int p0 = blockIdx.x * 16;
  int b = p0 >> 12, sp0 = p0 & 4095;
  f32x4 acc[10];
#pragma unroll
  for (int n = 0; n < 10; n++) acc[n] = (f32x4){0.f, 0.f, 0.f, 0.f};
  for (int kk = 0; kk < 5; kk++) {
    int k0 = kk * 32 + q * 8;
    bf16x8 a = (k0 < 152) ? *(const bf16x8*)(a2 + (size_t)(p0 + lr) * 152 + k0) : bzero8();
#pragma unroll
    for (int n = 0; n < 10; n++) {
      bf16x8 bf = *(const bf16x8*)(w3b + (size_t)(wid * 160 + n * 16 + lr) * 160 + k0);
      acc[n] = mfma16(a, bf, acc[n]);
    }
  }
#pragma unroll
  for (int n = 0; n < 10; n++) {
    int oc = wid * 160 + n * 16 + lr;
    if (oc < 608) {
      float inv = bnc[608 + oc], beta = bnc[1216 + oc];
      size_t gi = (((size_t)(b * 608 + oc)) << 12) + sp0 + q * 4;
      f32x4 xr = *(const f32x4*)(x + gi);
      f32x4 o;
#pragma unroll
      for (int i = 0; i < 4; i++) o[i] = fmaxf(acc[n][i] * inv + beta + xr[i], 0.f);
      *(f32x4*)(out + gi) = o;
    }
  }
}

extern "C" void kernel_launch(void* const* d_in, const int* in_sizes, int n_in,
                              void* d_out, int out_size, void* d_ws, size_t ws_size,
                              hipStream_t stream) {
  const float* x = (const float*)d_in[0];
  const float* w1 = (const float*)d_in[1];
  const float* w2 = (const float*)d_in[2];
  const float* wd = (const float*)d_in[3];
  const float* w3 = (const float*)d_in[4];
  const float* g1 = (const float*)d_in[5];
  const float* b1 = (const float*)d_in[6];
  const float* m1 = (const float*)d_in[7];
  const float* v1 = (const float*)d_in[8];
  const float* g2 = (const float*)d_in[9];
  const float* b2 = (const float*)d_in[10];
  const float* m2 = (const float*)d_in[11];
  const float* v2 = (const float*)d_in[12];
  const float* g3 = (const float*)d_in[13];
  const float* b3 = (const float*)d_in[14];
  const float* m3 = (const float*)d_in[15];
  const float* v3 = (const float*)d_in[16];

  char* ws = (char*)d_ws;
  bf16_t* w1b = (bf16_t*)(ws + 0);           // 194560
  bf16_t* w2b = (bf16_t*)(ws + 194560);      // 384*1440*2 = 1105920 -> 1300480
  bf16_t* wdb = (bf16_t*)(ws + 1300480);     // 192*1440*2 = 552960  -> 1853440
  bf16_t* w3b = (bf16_t*)(ws + 1853440);     // 204800               -> 2058240
  float* bnc = (float*)(ws + 2058240);       // 7296                 -> 2065536
  bf16_t* zbuf = (bf16_t*)(ws + 2065536);    // 64                   -> 2065600
  bf16_t* out1p = (bf16_t*)(ws + 2065600);   // 4*66*66*152*2 = 5297664 -> 7363264
  float* offs = (float*)(ws + 7363264);      // 16384*344*4 = 22544384 -> 29907648
  bf16_t* samp = (bf16_t*)(ws + 29907648);   // 16384*1440*2 = 47185920 -> 77093568
  bf16_t* a2 = (bf16_t*)(ws + 2065600);      // aliases out1p (dead after s3a)
  float* out = (float*)d_out;

  // zero ring (+zbuf) once per call
  hipMemsetAsync(ws + 2065536, 0, 64 + 5297664, stream);

  prep_weights<<<4020, 256, 0, stream>>>(w1, w2, wd, w3, w1b, w2b, wdb, w3b);
  prep_bn<<<1, 640, 0, stream>>>(g1, b1, m1, v1, g2, b2, m2, v2, g3, b3, m3, v3, bnc);
  s1_conv1<<<512, 256, 0, stream>>>(x, w1b, bnc, out1p);
  s2_offs<<<512, 256, 0, stream>>>(out1p, w2b, zbuf, offs);
  s3a_sample<<<10944, 256, 0, stream>>>(out1p, offs, samp);
  s3b_gemm<<<512, 256, 0, stream>>>(samp, wdb, bnc, a2);
  s4_conv3<<<1024, 256, 0, stream>>>(a2, w3b, bnc, x, out);
}